// Round 1
// baseline (6441.134 us; speedup 1.0000x reference)
//
#include <hip/hip_runtime.h>
#include <hip/hip_bf16.h>

// QLSTM persistent-kernel design:
//  - W (4 gates fused: [2048 rows][1024 K], rows f/i/u/o) converted to bf16 once.
//  - X converted to bf16 once.
//  - One persistent kernel, 128 WGs x 256 threads (1 WG ~ 1 CU, grid << 256 CUs
//    so co-residency is guaranteed; spin barrier with agent-scope atomics).
//  - Per step: phase G: WG w computes v[:, 16w..16w+15] (M=128,K=1024) via
//    mfma_16x16x32_bf16, W-slice persistent in LDS; grid barrier;
//    phase S: WG b scans row b (4 waves = 4 gates, shfl prefix-product),
//    updates c (registers), writes h (f32 to out, bf16 to state); grid barrier.
#define T_STEPS 256
#define BATCH   128
#define DIN     512
#define DH      512
#define NGATE   2048
#define NWG     128
#define WROW_P  1032   // padded LDS row stride (ushorts) -> 2-way bank alias only

typedef __attribute__((ext_vector_type(8))) short short8;
typedef __attribute__((ext_vector_type(4))) float f32x4;

#define OUT_HX ((size_t)T_STEPS * BATCH * DH)
#define OUT_CX (OUT_HX + (size_t)BATCH * DH)

__device__ inline ushort f2bf(float x) {
  uint u = __float_as_uint(x);
  u += 0x7fffu + ((u >> 16) & 1u);   // round-to-nearest-even
  return (ushort)(u >> 16);
}
__device__ inline float sigm(float x) { return 1.f / (1.f + __expf(-x)); }
__device__ inline float tanhf_(float x) { return 1.f - 2.f / (1.f + __expf(2.f * x)); }

// -------- prep kernels --------
__global__ void k_prep_w(const float* __restrict__ Wf, const float* __restrict__ Wi,
                         const float* __restrict__ Wu, const float* __restrict__ Wo,
                         ushort* __restrict__ Wb) {
  size_t i4 = ((size_t)blockIdx.x * 256 + threadIdx.x) * 4;
  if (i4 >= (size_t)NGATE * 1024) return;
  int row = (int)(i4 >> 10);
  int col = (int)(i4 & 1023);
  const float* W = (row < 512) ? Wf : (row < 1024) ? Wi : (row < 1536) ? Wu : Wo;
  int r = row & 511;
  float4 w = *(const float4*)&W[(size_t)r * 1024 + col];
  ushort4 o = make_ushort4(f2bf(w.x), f2bf(w.y), f2bf(w.z), f2bf(w.w));
  *(ushort4*)&Wb[i4] = o;
}

__global__ void k_prep_x(const float* __restrict__ X, ushort* __restrict__ Xb) {
  size_t i4 = ((size_t)blockIdx.x * 256 + threadIdx.x) * 4;
  if (i4 >= (size_t)T_STEPS * BATCH * DIN) return;
  float4 xv = *(const float4*)&X[i4];
  ushort4 o = make_ushort4(f2bf(xv.x), f2bf(xv.y), f2bf(xv.z), f2bf(xv.w));
  *(ushort4*)&Xb[i4] = o;
}

__global__ void k_prep_misc(const float* __restrict__ bf_, const float* __restrict__ tf_,
                            const float* __restrict__ bi_, const float* __restrict__ ti_,
                            const float* __restrict__ bu_, const float* __restrict__ tu_,
                            const float* __restrict__ bo_, const float* __restrict__ to_,
                            float* __restrict__ bt, ushort* __restrict__ hb,
                            int* __restrict__ flags) {
  int idx = blockIdx.x * 256 + threadIdx.x;
  if (idx < NGATE) {
    int g = idx >> 9, k = idx & 511;
    const float* b = (g == 0) ? bf_ : (g == 1) ? bi_ : (g == 2) ? bu_ : bo_;
    const float* t = (g == 0) ? tf_ : (g == 1) ? ti_ : (g == 2) ? tu_ : to_;
    bt[idx] = b[k] + t[k];
  }
  if (idx < BATCH * DH) hb[idx] = 0;   // h0 = 0 (bf16 zero)
  if (idx < 64) flags[idx] = 0;        // barrier count + flag (reset every launch)
}

// -------- grid barrier (sense via monotone epoch) --------
__device__ inline void grid_bar(int* flags, int epoch) {
  __syncthreads();                      // drain all waves' stores to L2
  if (threadIdx.x == 0) {
    int* cnt = flags;
    int* flg = flags + 32;              // separate cache line
    int prev = __hip_atomic_fetch_add(cnt, 1, __ATOMIC_ACQ_REL, __HIP_MEMORY_SCOPE_AGENT);
    if (prev == (int)gridDim.x - 1) {
      __hip_atomic_store(cnt, 0, __ATOMIC_RELAXED, __HIP_MEMORY_SCOPE_AGENT);
      __hip_atomic_store(flg, epoch, __ATOMIC_RELEASE, __HIP_MEMORY_SCOPE_AGENT);
    } else {
      while (__hip_atomic_load(flg, __ATOMIC_ACQUIRE, __HIP_MEMORY_SCOPE_AGENT) < epoch)
        __builtin_amdgcn_s_sleep(2);
    }
  }
  __syncthreads();
}

// -------- persistent main kernel --------
__global__ __launch_bounds__(256, 1) void qlstm_main(
    const ushort* __restrict__ Xb, const ushort* __restrict__ Wb,
    const float* __restrict__ bt, ushort* __restrict__ hb,
    float* __restrict__ v, int* __restrict__ flags, float* __restrict__ out) {
  const int wg   = blockIdx.x;        // 0..127: N-slice owner (G) and batch row (S)
  const int tid  = threadIdx.x;
  const int lane = tid & 63;
  const int wave = tid >> 6;          // 0..3
  const int n0   = wg * 16;

  __shared__ ushort lds_W[16 * WROW_P];   // 33 KB, persistent W slice
  __shared__ float  lds_bt[NGATE];        // 8 KB, bias+theta fused
  __shared__ float  lds_g[4 * DH];        // 8 KB, gate exchange

  // Load W slice once (rows n0..n0+15, K=1024), padded rows kill bank conflicts.
  for (int i = tid; i < 16 * 128; i += 256) {
    int r = i >> 7, c = (i & 127) << 3;
    short8 w = *(const short8*)&Wb[(size_t)(n0 + r) * 1024 + c];
    *(short8*)&lds_W[r * WROW_P + c] = w;
  }
  for (int i = tid; i < NGATE; i += 256) lds_bt[i] = bt[i];
  __syncthreads();

  float c0 = 0.f, c1 = 0.f;   // cell state for row wg, elems 2*tid, 2*tid+1
  int ep = 0;

  const int arow = lane & 15;
  const int kx   = (lane >> 4) << 3;   // 0,8,16,24
  const int m0   = wave * 32 + arow;   // A row for m-tile pair of this wave

  for (int t = 0; t < T_STEPS; ++t) {
    // ---------- phase G: v[:, n0..n0+15] = [Xb_t | h] @ Wslice^T ----------
    f32x4 acc0 = {0.f, 0.f, 0.f, 0.f};
    f32x4 acc1 = {0.f, 0.f, 0.f, 0.f};
    const ushort* Xt = Xb + (size_t)t * (BATCH * DIN);
#pragma unroll 4
    for (int ks = 0; ks < 16; ++ks) {          // x-part, K 0..511
      const int kb = ks * 32 + kx;
      short8 a0 = *(const short8*)(Xt + (size_t)m0 * DIN + kb);
      short8 a1 = *(const short8*)(Xt + (size_t)(m0 + 16) * DIN + kb);
      short8 b8 = *(const short8*)&lds_W[arow * WROW_P + kb];
      acc0 = __builtin_amdgcn_mfma_f32_16x16x32_bf16(a0, b8, acc0, 0, 0, 0);
      acc1 = __builtin_amdgcn_mfma_f32_16x16x32_bf16(a1, b8, acc1, 0, 0, 0);
    }
#pragma unroll 4
    for (int ks = 16; ks < 32; ++ks) {         // h-part, K 512..1023
      const int kb = ks * 32 + kx;
      const ushort* hsrc = hb + (kb - 512);
      short8 a0 = *(const short8*)(hsrc + (size_t)m0 * DH);
      short8 a1 = *(const short8*)(hsrc + (size_t)(m0 + 16) * DH);
      short8 b8 = *(const short8*)&lds_W[arow * WROW_P + kb];
      acc0 = __builtin_amdgcn_mfma_f32_16x16x32_bf16(a0, b8, acc0, 0, 0, 0);
      acc1 = __builtin_amdgcn_mfma_f32_16x16x32_bf16(a1, b8, acc1, 0, 0, 0);
    }
    {
      // C/D layout: col = lane&15, row = (lane>>4)*4 + reg
      const int rbase = wave * 32 + ((lane >> 4) << 2);
      float* vp = v + (size_t)rbase * NGATE + n0 + arow;
#pragma unroll
      for (int r = 0; r < 4; ++r) {
        vp[(size_t)r * NGATE]        = acc0[r];
        vp[(size_t)(r + 16) * NGATE] = acc1[r];
      }
    }
    grid_bar(flags, ++ep);

    // ---------- phase S: row wg, wave = gate ----------
    {
      const int g  = wave;
      const int e0 = lane << 3;
      const float* vrow = v + (size_t)wg * NGATE + g * DH + e0;
      float4 vA = *(const float4*)(vrow);
      float4 vB = *(const float4*)(vrow + 4);
      const float* btp = &lds_bt[g * DH + e0];
      float p0 = __cosf(vA.x + btp[0]);
      float p1 = __cosf(vA.y + btp[1]);
      float p2 = __cosf(vA.z + btp[2]);
      float p3 = __cosf(vA.w + btp[3]);
      float p4 = __cosf(vB.x + btp[4]);
      float p5 = __cosf(vB.y + btp[5]);
      float p6 = __cosf(vB.z + btp[6]);
      float p7 = __cosf(vB.w + btp[7]);
      float q0 = p0, q1 = q0 * p1, q2 = q1 * p2, q3 = q2 * p3;
      float q4 = q3 * p4, q5 = q4 * p5, q6 = q5 * p6, q7 = q6 * p7;
      // wave-wide inclusive prefix product of per-lane totals
      float a = q7;
#pragma unroll
      for (int off = 1; off < 64; off <<= 1) {
        float o = __shfl_up(a, off);
        a = (lane >= off) ? a * o : a;
      }
      float ex = __shfl_up(a, 1);
      ex = (lane == 0) ? 1.f : ex;
      float G0 = ex * q0, G1 = ex * q1, G2 = ex * q2, G3 = ex * q3;
      float G4 = ex * q4, G5 = ex * q5, G6 = ex * q6, G7 = ex * q7;
      float4 r0, r1;
      if (g == 2) {  // update gate -> tanh
        r0 = make_float4(tanhf_(G0), tanhf_(G1), tanhf_(G2), tanhf_(G3));
        r1 = make_float4(tanhf_(G4), tanhf_(G5), tanhf_(G6), tanhf_(G7));
      } else {       // f, i, o -> sigmoid
        r0 = make_float4(sigm(G0), sigm(G1), sigm(G2), sigm(G3));
        r1 = make_float4(sigm(G4), sigm(G5), sigm(G6), sigm(G7));
      }
      *(float4*)&lds_g[g * DH + e0]     = r0;
      *(float4*)&lds_g[g * DH + e0 + 4] = r1;
    }
    __syncthreads();
    {
      const int k = tid << 1;
      float f0 = lds_g[0 * DH + k], f1 = lds_g[0 * DH + k + 1];
      float i0 = lds_g[1 * DH + k], i1 = lds_g[1 * DH + k + 1];
      float u0 = lds_g[2 * DH + k], u1 = lds_g[2 * DH + k + 1];
      float o0 = lds_g[3 * DH + k], o1 = lds_g[3 * DH + k + 1];
      c0 = f0 * c0 + i0 * u0;
      c1 = f1 * c1 + i1 * u1;
      float h0 = o0 * tanhf_(c0);
      float h1 = o1 * tanhf_(c1);
      float2 hp = make_float2(h0, h1);
      *(float2*)&out[((size_t)t * BATCH + wg) * DH + k] = hp;
      uint hbits = ((uint)f2bf(h1) << 16) | (uint)f2bf(h0);
      ((uint*)hb)[((size_t)wg * DH + k) >> 1] = hbits;
      if (t == T_STEPS - 1) {
        *(float2*)&out[OUT_HX + (size_t)wg * DH + k] = hp;
        float2 cp = make_float2(c0, c1);
        *(float2*)&out[OUT_CX + (size_t)wg * DH + k] = cp;
      }
    }
    grid_bar(flags, ++ep);
  }
}

extern "C" void kernel_launch(void* const* d_in, const int* in_sizes, int n_in,
                              void* d_out, int out_size, void* d_ws, size_t ws_size,
                              hipStream_t stream) {
  const float* X  = (const float*)d_in[0];
  const float* Wf = (const float*)d_in[1];
  const float* bf = (const float*)d_in[2];
  const float* tf = (const float*)d_in[3];
  const float* Wi = (const float*)d_in[4];
  const float* bi = (const float*)d_in[5];
  const float* ti = (const float*)d_in[6];
  const float* Wu = (const float*)d_in[7];
  const float* bu = (const float*)d_in[8];
  const float* tu = (const float*)d_in[9];
  const float* Wo = (const float*)d_in[10];
  const float* bo = (const float*)d_in[11];
  const float* to = (const float*)d_in[12];

  char* ws = (char*)d_ws;
  // ws layout (all 256B-aligned):
  ushort* Wb   = (ushort*)(ws);               //  4,194,304 B
  ushort* Xb   = (ushort*)(ws + 4194304);     // 33,554,432 B
  float*  bt   = (float*) (ws + 37748736);    //      8,192 B
  ushort* hb   = (ushort*)(ws + 37756928);    //    131,072 B
  float*  v    = (float*) (ws + 37888000);    //  1,048,576 B
  int*    flags= (int*)   (ws + 38936576);    //        256 B
  float*  out  = (float*)d_out;

  k_prep_w<<<dim3((NGATE * 1024 / 4 + 255) / 256), dim3(256), 0, stream>>>(Wf, Wi, Wu, Wo, Wb);
  k_prep_x<<<dim3((T_STEPS * BATCH * DIN / 4 + 255) / 256), dim3(256), 0, stream>>>(X, Xb);
  k_prep_misc<<<dim3(256), dim3(256), 0, stream>>>(bf, tf, bi, ti, bu, tu, bo, to, bt, hb, flags);
  qlstm_main<<<dim3(NWG), dim3(256), 0, stream>>>(Xb, Wb, bt, hb, v, flags, out);
}

// Round 2
// 4670.968 us; speedup vs baseline: 1.3790x; 1.3790x over previous
//
#include <hip/hip_runtime.h>
#include <hip/hip_bf16.h>

// R2: 8 independent clusters (batch is embarrassingly parallel across rows!).
//  - cluster c = blockIdx%8 (matches HW round-robin block->XCD: cluster-local
//    v/h/flag traffic stays in one XCD's L2; heuristic only, agent-scope keeps
//    it correct regardless of placement).
//  - cluster = 32 WGs x 256 thr; owns batch rows [16c,16c+16).
//  - WG (member m) owns fused-gate cols [64m,64m+64); W slice lives in 128
//    VGPRs as persistent MFMA B-frags (no LDS, no lgkmcnt in GEMM).
//  - per step: h-part MFMA -> v write -> barA(arrive; only scan WGs wait) ->
//    members 0..15 scan row m (cumprod/activations, c in regs, write h) ->
//    barB arrive -> x-part MFMA of t+1 (overlapped, needs no h) -> barB wait.
//  - barriers: 32-participant, ACQ_REL arrive (once/WG), RELAXED spin +
//    single ACQUIRE fence on exit (no per-poll cache invalidates).
#define T_STEPS 256
#define BATCH   128
#define DIN     512
#define DH      512
#define NGATE   2048
#define NCL     8
#define WPC     32
#define ROWS_CL 16
#define NWG     (NCL * WPC)

typedef __attribute__((ext_vector_type(8))) short short8;
typedef __attribute__((ext_vector_type(4))) float f32x4;

#define OUT_HX ((size_t)T_STEPS * BATCH * DH)
#define OUT_CX (OUT_HX + (size_t)BATCH * DH)

// ---- ws layout ----
#define WB_OFF    0
#define XB_OFF    (4 * 1024 * 1024)
#define BT_OFF    (XB_OFF + 32 * 1024 * 1024)
#define CL_OFF    (BT_OFF + 8192)
#define CL_STRIDE (160 * 1024)
#define CLV_OFF   0                 // v: 16*2048*4 = 131072 B
#define CLH_OFF   131072            // h: 16*512*2  =  16384 B
#define CLF_OFF   147456            // flags: 1024 B

__device__ inline ushort f2bf(float x) {
  uint u = __float_as_uint(x);
  u += 0x7fffu + ((u >> 16) & 1u);
  return (ushort)(u >> 16);
}
__device__ inline float sigm(float x) { return 1.f / (1.f + __expf(-x)); }
__device__ inline float tanhf_(float x) { return 1.f - 2.f / (1.f + __expf(2.f * x)); }

// -------- prep kernels --------
__global__ void k_prep_w(const float* __restrict__ Wf, const float* __restrict__ Wi,
                         const float* __restrict__ Wu, const float* __restrict__ Wo,
                         ushort* __restrict__ Wb) {
  size_t i4 = ((size_t)blockIdx.x * 256 + threadIdx.x) * 4;
  if (i4 >= (size_t)NGATE * 1024) return;
  int row = (int)(i4 >> 10);
  int col = (int)(i4 & 1023);
  const float* W = (row < 512) ? Wf : (row < 1024) ? Wi : (row < 1536) ? Wu : Wo;
  int r = row & 511;
  float4 w = *(const float4*)&W[(size_t)r * 1024 + col];
  ushort4 o = make_ushort4(f2bf(w.x), f2bf(w.y), f2bf(w.z), f2bf(w.w));
  *(ushort4*)&Wb[i4] = o;
}

__global__ void k_prep_x(const float* __restrict__ X, ushort* __restrict__ Xb) {
  size_t i4 = ((size_t)blockIdx.x * 256 + threadIdx.x) * 4;
  if (i4 >= (size_t)T_STEPS * BATCH * DIN) return;
  float4 xv = *(const float4*)&X[i4];
  ushort4 o = make_ushort4(f2bf(xv.x), f2bf(xv.y), f2bf(xv.z), f2bf(xv.w));
  *(ushort4*)&Xb[i4] = o;
}

__global__ void k_prep_misc(const float* __restrict__ bf_, const float* __restrict__ tf_,
                            const float* __restrict__ bi_, const float* __restrict__ ti_,
                            const float* __restrict__ bu_, const float* __restrict__ tu_,
                            const float* __restrict__ bo_, const float* __restrict__ to_,
                            float* __restrict__ bt, char* __restrict__ clbase) {
  int idx = blockIdx.x * 256 + threadIdx.x;
  if (idx < NGATE) {
    int g = idx >> 9, k = idx & 511;
    const float* b = (g == 0) ? bf_ : (g == 1) ? bi_ : (g == 2) ? bu_ : bo_;
    const float* t = (g == 0) ? tf_ : (g == 1) ? ti_ : (g == 2) ? tu_ : to_;
    bt[idx] = b[k] + t[k];
  }
  if (idx < NCL * 4096) {  // zero h (16*512 bf16 = 4096 uints per cluster)
    int c = idx >> 12, w = idx & 4095;
    ((uint*)(clbase + (size_t)c * CL_STRIDE + CLH_OFF))[w] = 0u;
  }
  if (idx < NCL * 256) {   // zero flags (256 ints per cluster), every launch
    int c = idx >> 8, w = idx & 255;
    ((int*)(clbase + (size_t)c * CL_STRIDE + CLF_OFF))[w] = 0;
  }
}

// -------- cluster barrier: split arrive/wait --------
__device__ inline void bar_arrive(int* cnt, int* flg, int epoch) {
  __syncthreads();   // all waves' stores drained (vmcnt0 per wave before s_barrier)
  if (threadIdx.x == 0) {
    int prev = __hip_atomic_fetch_add(cnt, 1, __ATOMIC_ACQ_REL, __HIP_MEMORY_SCOPE_AGENT);
    if (prev == WPC - 1) {
      __hip_atomic_store(cnt, 0, __ATOMIC_RELAXED, __HIP_MEMORY_SCOPE_AGENT);
      __hip_atomic_store(flg, epoch, __ATOMIC_RELEASE, __HIP_MEMORY_SCOPE_AGENT);
    }
  }
}
__device__ inline void bar_wait(const int* flg, int epoch) {
  if (threadIdx.x == 0) {
    while (__hip_atomic_load(flg, __ATOMIC_RELAXED, __HIP_MEMORY_SCOPE_AGENT) < epoch)
      __builtin_amdgcn_s_sleep(1);
    __builtin_amdgcn_fence(__ATOMIC_ACQUIRE, "agent");  // one L1 inv, not per-poll
  }
  __syncthreads();
}

// -------- persistent main kernel --------
__global__ __launch_bounds__(256, 1) void qlstm_main(
    const ushort* __restrict__ Xb, const ushort* __restrict__ Wb,
    const float* __restrict__ bt, char* __restrict__ clbase,
    float* __restrict__ out) {
  const int bid  = blockIdx.x;
  const int c    = bid & 7;        // cluster (~XCD)
  const int mem  = bid >> 3;       // 0..31
  const int tid  = threadIdx.x;
  const int lane = tid & 63;
  const int wave = tid >> 6;

  char*   cl   = clbase + (size_t)c * CL_STRIDE;
  float*  v_cl = (float*)(cl + CLV_OFF);
  ushort* h_cl = (ushort*)(cl + CLH_OFF);
  int*    cntA = (int*)(cl + CLF_OFF);
  int*    flgA = cntA + 32;
  int*    cntB = cntA + 64;
  int*    flgB = cntA + 96;

  const int nb    = mem * 64 + wave * 16;  // this wave's fused-gate col base
  const int ar    = lane & 15;
  const int kx    = (lane >> 4) << 3;
  const int crow0 = c * ROWS_CL;

  // persistent B fragments: cols nb..nb+15 x K=1024 -> 32 frags (128 VGPR)
  short8 bfrag[32];
#pragma unroll
  for (int kt = 0; kt < 32; ++kt)
    bfrag[kt] = *(const short8*)&Wb[(size_t)(nb + ar) * 1024 + kt * 32 + kx];

  // scan-side constants (bias+theta) in registers
  float btr[8];
  {
    const int e0 = lane << 3;
#pragma unroll
    for (int j = 0; j < 8; ++j) btr[j] = bt[wave * DH + e0 + j];
  }

  __shared__ float lds_g[4 * DH];

  const int row = crow0 + mem;  // batch row (valid when mem<16)
  float c0 = 0.f, c1 = 0.f;
  int epA = 0, epB = 0;

  f32x4 accE = {0.f, 0.f, 0.f, 0.f}, accO = {0.f, 0.f, 0.f, 0.f};

#define XPART(TT) do {                                                        \
    accE = (f32x4){0.f, 0.f, 0.f, 0.f};                                       \
    accO = (f32x4){0.f, 0.f, 0.f, 0.f};                                       \
    const ushort* Ax = Xb + ((size_t)(TT) * BATCH + crow0 + ar) * DIN + kx;   \
    _Pragma("unroll")                                                         \
    for (int kt = 0; kt < 16; kt += 2) {                                      \
      short8 a0 = *(const short8*)(Ax + kt * 32);                             \
      short8 a1 = *(const short8*)(Ax + (kt + 1) * 32);                       \
      accE = __builtin_amdgcn_mfma_f32_16x16x32_bf16(a0, bfrag[kt], accE, 0, 0, 0);     \
      accO = __builtin_amdgcn_mfma_f32_16x16x32_bf16(a1, bfrag[kt + 1], accO, 0, 0, 0); \
    }                                                                         \
  } while (0)

  XPART(0);

  for (int t = 0; t < T_STEPS; ++t) {
    // ---- h-part GEMM (h ready: t=0 zeros from prep, else barB of t-1) ----
    {
      const ushort* Ah = h_cl + ar * DH + kx;
#pragma unroll
      for (int kt = 16; kt < 32; kt += 2) {
        short8 a0 = *(const short8*)(Ah + (kt - 16) * 32);
        short8 a1 = *(const short8*)(Ah + (kt - 15) * 32);
        accE = __builtin_amdgcn_mfma_f32_16x16x32_bf16(a0, bfrag[kt], accE, 0, 0, 0);
        accO = __builtin_amdgcn_mfma_f32_16x16x32_bf16(a1, bfrag[kt + 1], accO, 0, 0, 0);
      }
    }
    // ---- write v slice: C row=(lane>>4)*4+r, col=lane&15 ----
    {
      const int rbase = (lane >> 4) << 2;
      float* vp = v_cl + (size_t)rbase * NGATE + nb + ar;
#pragma unroll
      for (int r = 0; r < 4; ++r)
        vp[(size_t)r * NGATE] = accE[r] + accO[r];
    }
    bar_arrive(cntA, flgA, ++epA);
    ++epB;

    if (mem < ROWS_CL) {
      bar_wait(flgA, epA);   // need everyone's v for my row
      // ---- scan row `mem`: wave = gate ----
      {
        const int g  = wave;
        const int e0 = lane << 3;
        const float* vrow = v_cl + (size_t)mem * NGATE + g * DH + e0;
        float4 vA = *(const float4*)(vrow);
        float4 vB = *(const float4*)(vrow + 4);
        float p0 = __cosf(vA.x + btr[0]);
        float p1 = __cosf(vA.y + btr[1]);
        float p2 = __cosf(vA.z + btr[2]);
        float p3 = __cosf(vA.w + btr[3]);
        float p4 = __cosf(vB.x + btr[4]);
        float p5 = __cosf(vB.y + btr[5]);
        float p6 = __cosf(vB.z + btr[6]);
        float p7 = __cosf(vB.w + btr[7]);
        float q0 = p0, q1 = q0 * p1, q2 = q1 * p2, q3 = q2 * p3;
        float q4 = q3 * p4, q5 = q4 * p5, q6 = q5 * p6, q7 = q6 * p7;
        float a = q7;
#pragma unroll
        for (int off = 1; off < 64; off <<= 1) {
          float o = __shfl_up(a, off);
          a = (lane >= off) ? a * o : a;
        }
        float ex = __shfl_up(a, 1);
        ex = (lane == 0) ? 1.f : ex;
        float G0 = ex * q0, G1 = ex * q1, G2 = ex * q2, G3 = ex * q3;
        float G4 = ex * q4, G5 = ex * q5, G6 = ex * q6, G7 = ex * q7;
        float4 r0, r1;
        if (g == 2) {
          r0 = make_float4(tanhf_(G0), tanhf_(G1), tanhf_(G2), tanhf_(G3));
          r1 = make_float4(tanhf_(G4), tanhf_(G5), tanhf_(G6), tanhf_(G7));
        } else {
          r0 = make_float4(sigm(G0), sigm(G1), sigm(G2), sigm(G3));
          r1 = make_float4(sigm(G4), sigm(G5), sigm(G6), sigm(G7));
        }
        *(float4*)&lds_g[g * DH + e0]     = r0;
        *(float4*)&lds_g[g * DH + e0 + 4] = r1;
      }
      __syncthreads();
      {
        const int k = tid << 1;
        float f0 = lds_g[0 * DH + k], f1 = lds_g[0 * DH + k + 1];
        float i0 = lds_g[1 * DH + k], i1 = lds_g[1 * DH + k + 1];
        float u0 = lds_g[2 * DH + k], u1 = lds_g[2 * DH + k + 1];
        float o0 = lds_g[3 * DH + k], o1 = lds_g[3 * DH + k + 1];
        c0 = f0 * c0 + i0 * u0;
        c1 = f1 * c1 + i1 * u1;
        float h0 = o0 * tanhf_(c0);
        float h1 = o1 * tanhf_(c1);
        float2 hp = make_float2(h0, h1);
        *(float2*)&out[((size_t)t * BATCH + row) * DH + k] = hp;
        uint hbits = ((uint)f2bf(h1) << 16) | (uint)f2bf(h0);
        ((uint*)h_cl)[((size_t)mem * DH + k) >> 1] = hbits;
        if (t == T_STEPS - 1) {
          *(float2*)&out[OUT_HX + (size_t)row * DH + k] = hp;
          float2 cp = make_float2(c0, c1);
          *(float2*)&out[OUT_CX + (size_t)row * DH + k] = cp;
        }
      }
      bar_arrive(cntB, flgB, epB);  // my h row written
    } else {
      bar_arrive(cntB, flgB, epB);  // no h to write; arrive immediately
    }

    // ---- overlapped x-part of t+1 (needs no h) ----
    if (t + 1 < T_STEPS) XPART(t + 1);

    bar_wait(flgB, epB);  // all h rows ready for next h-part
  }
#undef XPART
}

extern "C" void kernel_launch(void* const* d_in, const int* in_sizes, int n_in,
                              void* d_out, int out_size, void* d_ws, size_t ws_size,
                              hipStream_t stream) {
  const float* X  = (const float*)d_in[0];
  const float* Wf = (const float*)d_in[1];
  const float* bf = (const float*)d_in[2];
  const float* tf = (const float*)d_in[3];
  const float* Wi = (const float*)d_in[4];
  const float* bi = (const float*)d_in[5];
  const float* ti = (const float*)d_in[6];
  const float* Wu = (const float*)d_in[7];
  const float* bu = (const float*)d_in[8];
  const float* tu = (const float*)d_in[9];
  const float* Wo = (const float*)d_in[10];
  const float* bo = (const float*)d_in[11];
  const float* to = (const float*)d_in[12];

  char* ws = (char*)d_ws;
  ushort* Wb     = (ushort*)(ws + WB_OFF);
  ushort* Xb     = (ushort*)(ws + XB_OFF);
  float*  bt     = (float*)(ws + BT_OFF);
  char*   clbase = ws + CL_OFF;
  float*  out    = (float*)d_out;

  k_prep_w<<<dim3((NGATE * 1024 / 4 + 255) / 256), dim3(256), 0, stream>>>(Wf, Wi, Wu, Wo, Wb);
  k_prep_x<<<dim3((T_STEPS * BATCH * DIN / 4 + 255) / 256), dim3(256), 0, stream>>>(X, Xb);
  k_prep_misc<<<dim3(256), dim3(256), 0, stream>>>(bf, tf, bi, ti, bu, tu, bo, to, bt, clbase);
  qlstm_main<<<dim3(NWG), dim3(256), 0, stream>>>(Xb, Wb, bt, clbase, out);
}

// Round 3
// 2434.904 us; speedup vs baseline: 2.6453x; 1.9183x over previous
//
#include <hip/hip_runtime.h>
#include <hip/hip_bf16.h>

// R3: same 8-cluster x 32-WG geometry as R2; sync transport rebuilt.
//  - All cross-WG data (v, h) via RELAXED AGENT-scope atomics (sc0 sc1 ->
//    coherence point directly). NO release/acquire fences => no per-barrier
//    buffer_wbl2 L2 flush (R2's 365 MB/step HBM write-through) and no
//    L1/L2 invalidates.
//  - Barrier = slot-store + lane-parallel poll (no serialized fetch_add).
//    Ordering: __syncthreads() drains vmcnt (sc-stores ack'd at coherence
//    point) before the relaxed flag store; consumers poll flag, then issue
//    dependent sc-loads. Placement-independent correctness.
//  - W slice in LDS (128 KB, XOR-swizzled, 2-way conflict = free) instead of
//    VGPRs: R2's VGPR_Count=112 proved the compiler was re-fetching W from L2
//    inside the loop, on the h-GEMM critical path.
#define T_STEPS 256
#define BATCH   128
#define DIN     512
#define DH      512
#define NGATE   2048
#define NCL     8
#define WPC     32
#define ROWS_CL 16
#define NWG     (NCL * WPC)

typedef __attribute__((ext_vector_type(8))) short short8;
typedef __attribute__((ext_vector_type(4))) float f32x4;
typedef unsigned long long u64;

#define OUT_HX ((size_t)T_STEPS * BATCH * DH)
#define OUT_CX (OUT_HX + (size_t)BATCH * DH)

// ---- ws layout ----
#define WB_OFF    0
#define XB_OFF    (4 * 1024 * 1024)
#define BT_OFF    (XB_OFF + 32 * 1024 * 1024)
#define CL_OFF    (BT_OFF + 8192)
#define CL_STRIDE (160 * 1024)
#define CLV_OFF   0                 // v: 16*2048*4 = 131072 B
#define CLH_OFF   131072            // h: 16*512*2  =  16384 B
#define CLF_OFF   147456            // slots: 1024 B (A at +0, B at +256)

#define LDS_W_BYTES 131072          // 64 cols x 1024 K x bf16, swizzled
#define LDS_TOTAL   (LDS_W_BYTES + 4 * DH * 4)

__device__ inline ushort f2bf(float x) {
  uint u = __float_as_uint(x);
  u += 0x7fffu + ((u >> 16) & 1u);
  return (ushort)(u >> 16);
}
__device__ inline float sigm(float x) { return 1.f / (1.f + __expf(-x)); }
__device__ inline float tanhf_(float x) { return 1.f - 2.f / (1.f + __expf(2.f * x)); }

// relaxed agent-scope (coherence-point) data movement
__device__ inline u64 ald64(const u64* p) {
  return __hip_atomic_load(p, __ATOMIC_RELAXED, __HIP_MEMORY_SCOPE_AGENT);
}
__device__ inline void ast32(uint* p, uint v) {
  __hip_atomic_store(p, v, __ATOMIC_RELAXED, __HIP_MEMORY_SCOPE_AGENT);
}
__device__ inline int aldi(const int* p) {
  return __hip_atomic_load(p, __ATOMIC_RELAXED, __HIP_MEMORY_SCOPE_AGENT);
}
__device__ inline void asti(int* p, int v) {
  __hip_atomic_store(p, v, __ATOMIC_RELAXED, __HIP_MEMORY_SCOPE_AGENT);
}

union U16 { u64 q[2]; short8 s; };
union UF2 { u64 q; float f[2]; };

// -------- prep kernels --------
__global__ void k_prep_w(const float* __restrict__ Wf, const float* __restrict__ Wi,
                         const float* __restrict__ Wu, const float* __restrict__ Wo,
                         ushort* __restrict__ Wb) {
  size_t i4 = ((size_t)blockIdx.x * 256 + threadIdx.x) * 4;
  if (i4 >= (size_t)NGATE * 1024) return;
  int row = (int)(i4 >> 10);
  int col = (int)(i4 & 1023);
  const float* W = (row < 512) ? Wf : (row < 1024) ? Wi : (row < 1536) ? Wu : Wo;
  int r = row & 511;
  float4 w = *(const float4*)&W[(size_t)r * 1024 + col];
  ushort4 o = make_ushort4(f2bf(w.x), f2bf(w.y), f2bf(w.z), f2bf(w.w));
  *(ushort4*)&Wb[i4] = o;
}

__global__ void k_prep_x(const float* __restrict__ X, ushort* __restrict__ Xb) {
  size_t i4 = ((size_t)blockIdx.x * 256 + threadIdx.x) * 4;
  if (i4 >= (size_t)T_STEPS * BATCH * DIN) return;
  float4 xv = *(const float4*)&X[i4];
  ushort4 o = make_ushort4(f2bf(xv.x), f2bf(xv.y), f2bf(xv.z), f2bf(xv.w));
  *(ushort4*)&Xb[i4] = o;
}

__global__ void k_prep_misc(const float* __restrict__ bf_, const float* __restrict__ tf_,
                            const float* __restrict__ bi_, const float* __restrict__ ti_,
                            const float* __restrict__ bu_, const float* __restrict__ tu_,
                            const float* __restrict__ bo_, const float* __restrict__ to_,
                            float* __restrict__ bt, char* __restrict__ clbase) {
  int idx = blockIdx.x * 256 + threadIdx.x;
  if (idx < NGATE) {
    int g = idx >> 9, k = idx & 511;
    const float* b = (g == 0) ? bf_ : (g == 1) ? bi_ : (g == 2) ? bu_ : bo_;
    const float* t = (g == 0) ? tf_ : (g == 1) ? ti_ : (g == 2) ? tu_ : to_;
    bt[idx] = b[k] + t[k];
  }
  if (idx < NCL * 4096) {  // zero h (16*512 bf16 = 4096 uints per cluster)
    int c = idx >> 12, w = idx & 4095;
    ((uint*)(clbase + (size_t)c * CL_STRIDE + CLH_OFF))[w] = 0u;
  }
  if (idx < NCL * 256) {   // zero slots (256 ints per cluster), every launch
    int c = idx >> 8, w = idx & 255;
    ((int*)(clbase + (size_t)c * CL_STRIDE + CLF_OFF))[w] = 0;
  }
}

// -------- persistent main kernel --------
__global__ __launch_bounds__(256, 1) void qlstm_main(
    const ushort* __restrict__ Xb, const ushort* __restrict__ Wb,
    const float* __restrict__ bt, char* __restrict__ clbase,
    float* __restrict__ out) {
  extern __shared__ char smem[];
  ushort* wlds  = (ushort*)smem;                    // [64 cols][1024 K] swizzled
  float*  lds_g = (float*)(smem + LDS_W_BYTES);     // [4][512] gate exchange

  const int bid  = blockIdx.x;
  const int c    = bid & 7;
  const int mem  = bid >> 3;       // 0..31
  const int tid  = threadIdx.x;
  const int lane = tid & 63;
  const int wave = tid >> 6;

  char*   cl    = clbase + (size_t)c * CL_STRIDE;
  float*  v_cl  = (float*)(cl + CLV_OFF);
  u64*    h_cl  = (u64*)(cl + CLH_OFF);
  uint*   h_cl32= (uint*)(cl + CLH_OFF);
  int*    slotA = (int*)(cl + CLF_OFF);        // [32]
  int*    slotB = (int*)(cl + CLF_OFF + 256);  // [16]

  const int nb    = mem * 64 + wave * 16;  // this wave's fused-gate col base
  const int ar    = lane & 15;
  const int kx    = (lane >> 4) << 3;      // 0,8,16,24 (ushort units)
  const int crow0 = c * ROWS_CL;
  const int row   = crow0 + mem;           // batch row (valid when mem<16)
  const int wrow  = wave * 16 + ar;        // local W col in LDS

  // ---- stage W slice into LDS (XOR-swizzled rows) ----
  {
    const char* wsrc = (const char*)(Wb + (size_t)(mem * 64) * 1024);
#pragma unroll
    for (int it = 0; it < 32; ++it) {
      int idx16 = it * 256 + tid;           // 8192 x 16B chunks
      int r  = idx16 >> 7;                  // 0..63
      int kb = (idx16 & 127) << 4;          // byte offset in row
      short8 w = *(const short8*)(wsrc + (size_t)r * 2048 + kb);
      *(short8*)((char*)wlds + (size_t)r * 2048 + (kb ^ ((r & 7) << 4))) = w;
    }
  }
  // swizzled B-frag read: col wrow, k-tile KT, 16B at k-byte (KT*64 + kx*2)
#define WFRAG(KT) (*(const short8*)((const char*)wlds + (size_t)wrow * 2048 + \
                    ((((KT) * 64) + (kx << 1)) ^ ((ar & 7) << 4))))

  float btr[8];
  {
    const int e0 = lane << 3;
#pragma unroll
    for (int j = 0; j < 8; ++j) btr[j] = bt[wave * DH + e0 + j];
  }
  __syncthreads();

  float c0 = 0.f, c1 = 0.f;
  f32x4 accE = {0.f, 0.f, 0.f, 0.f}, accO = {0.f, 0.f, 0.f, 0.f};

#define XPART(TT) do {                                                        \
    accE = (f32x4){0.f, 0.f, 0.f, 0.f};                                       \
    accO = (f32x4){0.f, 0.f, 0.f, 0.f};                                       \
    const ushort* Ax = Xb + ((size_t)(TT) * BATCH + crow0 + ar) * DIN + kx;   \
    _Pragma("unroll")                                                         \
    for (int kt = 0; kt < 16; kt += 2) {                                      \
      short8 a0 = *(const short8*)(Ax + kt * 32);                             \
      short8 a1 = *(const short8*)(Ax + (kt + 1) * 32);                       \
      accE = __builtin_amdgcn_mfma_f32_16x16x32_bf16(a0, WFRAG(kt), accE, 0, 0, 0);     \
      accO = __builtin_amdgcn_mfma_f32_16x16x32_bf16(a1, WFRAG(kt + 1), accO, 0, 0, 0); \
    }                                                                         \
  } while (0)

  XPART(0);

  for (int t = 0; t < T_STEPS; ++t) {
    const int ep = t + 1;
    // ---- h-part GEMM: A = h (coherence-point loads), B = LDS W frags ----
    {
      U16 af[16];
#pragma unroll
      for (int kt = 0; kt < 16; ++kt) {
        const u64* p = h_cl + (((size_t)ar * DH + kt * 32 + kx) >> 2);
        af[kt].q[0] = ald64(p);
        af[kt].q[1] = ald64(p + 1);
      }
#pragma unroll
      for (int kt = 0; kt < 16; kt += 2) {
        accE = __builtin_amdgcn_mfma_f32_16x16x32_bf16(af[kt].s,     WFRAG(16 + kt),     accE, 0, 0, 0);
        accO = __builtin_amdgcn_mfma_f32_16x16x32_bf16(af[kt + 1].s, WFRAG(16 + kt + 1), accO, 0, 0, 0);
      }
    }
    // ---- v slice store (coherence point): C row=(lane>>4)*4+r, col=ar ----
    {
      const int rbase = (lane >> 4) << 2;
      float* vp = v_cl + (size_t)rbase * NGATE + nb + ar;
#pragma unroll
      for (int r = 0; r < 4; ++r)
        ast32((uint*)&vp[(size_t)r * NGATE], __float_as_uint(accE[r] + accO[r]));
    }
    __syncthreads();   // drains vmcnt: sc-stores ack'd at coherence point
    if (tid == 0) asti(&slotA[mem], ep);

    if (mem < ROWS_CL) {
      // ---- wait for all 32 v slices ----
      if (wave == 0) {
        for (;;) {
          int s = (lane < WPC) ? aldi(&slotA[lane]) : ep;
          if (__all(s >= ep)) break;
          __builtin_amdgcn_s_sleep(1);
        }
      }
      __syncthreads();
      asm volatile("" ::: "memory");
      // ---- scan row `mem`: wave = gate ----
      {
        const int g  = wave;
        const int e0 = lane << 3;
        const u64* vr = (const u64*)(v_cl + (size_t)mem * NGATE + g * DH + e0);
        UF2 w0, w1, w2, w3;
        w0.q = ald64(vr);     w1.q = ald64(vr + 1);
        w2.q = ald64(vr + 2); w3.q = ald64(vr + 3);
        float p0 = __cosf(w0.f[0] + btr[0]);
        float p1 = __cosf(w0.f[1] + btr[1]);
        float p2 = __cosf(w1.f[0] + btr[2]);
        float p3 = __cosf(w1.f[1] + btr[3]);
        float p4 = __cosf(w2.f[0] + btr[4]);
        float p5 = __cosf(w2.f[1] + btr[5]);
        float p6 = __cosf(w3.f[0] + btr[6]);
        float p7 = __cosf(w3.f[1] + btr[7]);
        float q0 = p0, q1 = q0 * p1, q2 = q1 * p2, q3 = q2 * p3;
        float q4 = q3 * p4, q5 = q4 * p5, q6 = q5 * p6, q7 = q6 * p7;
        float a = q7;
#pragma unroll
        for (int off = 1; off < 64; off <<= 1) {
          float o = __shfl_up(a, off);
          a = (lane >= off) ? a * o : a;
        }
        float ex = __shfl_up(a, 1);
        ex = (lane == 0) ? 1.f : ex;
        float G0 = ex * q0, G1 = ex * q1, G2 = ex * q2, G3 = ex * q3;
        float G4 = ex * q4, G5 = ex * q5, G6 = ex * q6, G7 = ex * q7;
        float4 r0, r1;
        if (g == 2) {
          r0 = make_float4(tanhf_(G0), tanhf_(G1), tanhf_(G2), tanhf_(G3));
          r1 = make_float4(tanhf_(G4), tanhf_(G5), tanhf_(G6), tanhf_(G7));
        } else {
          r0 = make_float4(sigm(G0), sigm(G1), sigm(G2), sigm(G3));
          r1 = make_float4(sigm(G4), sigm(G5), sigm(G6), sigm(G7));
        }
        *(float4*)&lds_g[g * DH + e0]     = r0;
        *(float4*)&lds_g[g * DH + e0 + 4] = r1;
      }
      __syncthreads();
      {
        const int k = tid << 1;
        float f0 = lds_g[0 * DH + k], f1 = lds_g[0 * DH + k + 1];
        float i0 = lds_g[1 * DH + k], i1 = lds_g[1 * DH + k + 1];
        float u0 = lds_g[2 * DH + k], u1 = lds_g[2 * DH + k + 1];
        float o0 = lds_g[3 * DH + k], o1 = lds_g[3 * DH + k + 1];
        c0 = f0 * c0 + i0 * u0;
        c1 = f1 * c1 + i1 * u1;
        float h0 = o0 * tanhf_(c0);
        float h1 = o1 * tanhf_(c1);
        float2 hp = make_float2(h0, h1);
        *(float2*)&out[((size_t)t * BATCH + row) * DH + k] = hp;
        uint hbits = ((uint)f2bf(h1) << 16) | (uint)f2bf(h0);
        ast32(&h_cl32[((size_t)mem * DH + k) >> 1], hbits);
        if (t == T_STEPS - 1) {
          *(float2*)&out[OUT_HX + (size_t)row * DH + k] = hp;
          float2 cp = make_float2(c0, c1);
          *(float2*)&out[OUT_CX + (size_t)row * DH + k] = cp;
        }
      }
      __syncthreads();   // drain h sc-stores
      if (tid == 0) asti(&slotB[mem], ep);
    }

    if (t + 1 < T_STEPS) {
      // ---- overlapped x-part of t+1 (needs no h) ----
      XPART(t + 1);
      // ---- wait for all 16 h rows ----
      if (wave == 0) {
        for (;;) {
          int s = (lane < ROWS_CL) ? aldi(&slotB[lane]) : ep;
          if (__all(s >= ep)) break;
          __builtin_amdgcn_s_sleep(1);
        }
      }
      __syncthreads();
      asm volatile("" ::: "memory");
    }
  }
#undef XPART
#undef WFRAG
}

extern "C" void kernel_launch(void* const* d_in, const int* in_sizes, int n_in,
                              void* d_out, int out_size, void* d_ws, size_t ws_size,
                              hipStream_t stream) {
  const float* X  = (const float*)d_in[0];
  const float* Wf = (const float*)d_in[1];
  const float* bf = (const float*)d_in[2];
  const float* tf = (const float*)d_in[3];
  const float* Wi = (const float*)d_in[4];
  const float* bi = (const float*)d_in[5];
  const float* ti = (const float*)d_in[6];
  const float* Wu = (const float*)d_in[7];
  const float* bu = (const float*)d_in[8];
  const float* tu = (const float*)d_in[9];
  const float* Wo = (const float*)d_in[10];
  const float* bo = (const float*)d_in[11];
  const float* to = (const float*)d_in[12];

  char* ws = (char*)d_ws;
  ushort* Wb     = (ushort*)(ws + WB_OFF);
  ushort* Xb     = (ushort*)(ws + XB_OFF);
  float*  bt     = (float*)(ws + BT_OFF);
  char*   clbase = ws + CL_OFF;
  float*  out    = (float*)d_out;

  static bool attr_set = false;
  if (!attr_set) {
    hipFuncSetAttribute((const void*)qlstm_main,
                        hipFuncAttributeMaxDynamicSharedMemorySize, LDS_TOTAL);
    attr_set = true;
  }

  k_prep_w<<<dim3((NGATE * 1024 / 4 + 255) / 256), dim3(256), 0, stream>>>(Wf, Wi, Wu, Wo, Wb);
  k_prep_x<<<dim3((T_STEPS * BATCH * DIN / 4 + 255) / 256), dim3(256), 0, stream>>>(X, Xb);
  k_prep_misc<<<dim3(256), dim3(256), 0, stream>>>(bf, tf, bi, ti, bu, tu, bo, to, bt, clbase);
  qlstm_main<<<dim3(NWG), dim3(256), LDS_TOTAL, stream>>>(Xb, Wb, bt, clbase, out);
}

// Round 6
// 2082.608 us; speedup vs baseline: 3.0928x; 1.1692x over previous
//
#include <hip/hip_runtime.h>
#include <hip/hip_bf16.h>

// R6: R3's proven agent-scope transport (RELAXED __hip_atomic_* everywhere,
// no inline-asm memory ops, no XCD bootstrap), plus de-contended barriers:
//  - every arrival flag slot padded to 128 B (own MALL line). R3 packed 32
//    flags into 2 lines -> 32 serialized same-line coherence-point stores per
//    barrier + 512 lanes polling 2 lines. Padding parallelizes both.
//  - geometry unchanged: 8 clusters x 32 WGs, cluster owns 16 batch rows,
//    WG owns 64 fused-gate cols, W slice in LDS (XOR-swizzled), x-part GEMM
//    of step t+1 overlapped under the h-ready wait.
#define T_STEPS 256
#define BATCH   128
#define DIN     512
#define DH      512
#define NGATE   2048
#define NCL     8
#define WPC     32
#define ROWS_CL 16
#define NWG     (NCL * WPC)

typedef __attribute__((ext_vector_type(8))) short short8;
typedef __attribute__((ext_vector_type(4))) float f32x4;
typedef unsigned long long u64;

#define OUT_HX ((size_t)T_STEPS * BATCH * DH)
#define OUT_CX (OUT_HX + (size_t)BATCH * DH)

// ---- ws layout ----
#define WB_OFF    0
#define XB_OFF    (4 * 1024 * 1024)
#define BT_OFF    (XB_OFF + 32 * 1024 * 1024)
#define CL_OFF    (BT_OFF + 8192)
#define CL_STRIDE (160 * 1024)
#define CLV_OFF   0                  // v: 16*2048*4 = 131072 B
#define CLH_OFF   131072             // h: 16*512*2  =  16384 B
#define CLF_OFF   147456             // slotA: 32 slots x 128 B = 4096 B
#define CLFB_OFF  (CLF_OFF + 4096)   // slotB: 16 slots x 128 B = 2048 B
#define SLOT_STRIDE 32               // ints per slot (128 B)

#define LDS_W_BYTES 131072           // 64 cols x 1024 K x bf16, swizzled
#define LDS_TOTAL   (LDS_W_BYTES + 4 * DH * 4)

__device__ inline ushort f2bf(float x) {
  uint u = __float_as_uint(x);
  u += 0x7fffu + ((u >> 16) & 1u);
  return (ushort)(u >> 16);
}
__device__ inline float sigm(float x) { return 1.f / (1.f + __expf(-x)); }
__device__ inline float tanhf_(float x) { return 1.f - 2.f / (1.f + __expf(2.f * x)); }

// relaxed agent-scope (coherence-point) data movement — R3-proven
__device__ inline u64 ald64(const u64* p) {
  return __hip_atomic_load(p, __ATOMIC_RELAXED, __HIP_MEMORY_SCOPE_AGENT);
}
__device__ inline void ast32(uint* p, uint v) {
  __hip_atomic_store(p, v, __ATOMIC_RELAXED, __HIP_MEMORY_SCOPE_AGENT);
}
__device__ inline int aldi(const int* p) {
  return __hip_atomic_load(p, __ATOMIC_RELAXED, __HIP_MEMORY_SCOPE_AGENT);
}
__device__ inline void asti(int* p, int v) {
  __hip_atomic_store(p, v, __ATOMIC_RELAXED, __HIP_MEMORY_SCOPE_AGENT);
}

union U16 { u64 q[2]; short8 s; };
union UF2 { u64 q; float f[2]; };

// -------- prep kernels --------
__global__ void k_prep_w(const float* __restrict__ Wf, const float* __restrict__ Wi,
                         const float* __restrict__ Wu, const float* __restrict__ Wo,
                         ushort* __restrict__ Wb) {
  size_t i4 = ((size_t)blockIdx.x * 256 + threadIdx.x) * 4;
  if (i4 >= (size_t)NGATE * 1024) return;
  int row = (int)(i4 >> 10);
  int col = (int)(i4 & 1023);
  const float* W = (row < 512) ? Wf : (row < 1024) ? Wi : (row < 1536) ? Wu : Wo;
  int r = row & 511;
  float4 w = *(const float4*)&W[(size_t)r * 1024 + col];
  ushort4 o = make_ushort4(f2bf(w.x), f2bf(w.y), f2bf(w.z), f2bf(w.w));
  *(ushort4*)&Wb[i4] = o;
}

__global__ void k_prep_x(const float* __restrict__ X, ushort* __restrict__ Xb) {
  size_t i4 = ((size_t)blockIdx.x * 256 + threadIdx.x) * 4;
  if (i4 >= (size_t)T_STEPS * BATCH * DIN) return;
  float4 xv = *(const float4*)&X[i4];
  ushort4 o = make_ushort4(f2bf(xv.x), f2bf(xv.y), f2bf(xv.z), f2bf(xv.w));
  *(ushort4*)&Xb[i4] = o;
}

__global__ void k_prep_misc(const float* __restrict__ bf_, const float* __restrict__ tf_,
                            const float* __restrict__ bi_, const float* __restrict__ ti_,
                            const float* __restrict__ bu_, const float* __restrict__ tu_,
                            const float* __restrict__ bo_, const float* __restrict__ to_,
                            float* __restrict__ bt, char* __restrict__ clbase) {
  int idx = blockIdx.x * 256 + threadIdx.x;
  if (idx < NGATE) {
    int g = idx >> 9, k = idx & 511;
    const float* b = (g == 0) ? bf_ : (g == 1) ? bi_ : (g == 2) ? bu_ : bo_;
    const float* t = (g == 0) ? tf_ : (g == 1) ? ti_ : (g == 2) ? tu_ : to_;
    bt[idx] = b[k] + t[k];
  }
  if (idx < NCL * 4096) {  // zero h (16*512 bf16 = 4096 uints per cluster)
    int c = idx >> 12, w = idx & 4095;
    ((uint*)(clbase + (size_t)c * CL_STRIDE + CLH_OFF))[w] = 0u;
  }
  if (idx < NCL * 2048) {  // zero padded flag region (8192 B per cluster)
    int c = idx >> 11, w = idx & 2047;
    ((int*)(clbase + (size_t)c * CL_STRIDE + CLF_OFF))[w] = 0;
  }
}

// -------- persistent main kernel --------
__global__ __launch_bounds__(256, 1) void qlstm_main(
    const ushort* __restrict__ Xb, const ushort* __restrict__ Wb,
    const float* __restrict__ bt, char* __restrict__ clbase,
    float* __restrict__ out) {
  extern __shared__ char smem[];
  ushort* wlds  = (ushort*)smem;                    // [64 cols][1024 K] swizzled
  float*  lds_g = (float*)(smem + LDS_W_BYTES);     // [4][512] gate exchange

  const int bid  = blockIdx.x;
  const int c    = bid & 7;
  const int mem  = bid >> 3;       // 0..31
  const int tid  = threadIdx.x;
  const int lane = tid & 63;
  const int wave = tid >> 6;

  char*   cl    = clbase + (size_t)c * CL_STRIDE;
  float*  v_cl  = (float*)(cl + CLV_OFF);
  u64*    h_cl  = (u64*)(cl + CLH_OFF);
  uint*   h_cl32= (uint*)(cl + CLH_OFF);
  int*    slotA = (int*)(cl + CLF_OFF);        // [32] x 128B stride
  int*    slotB = (int*)(cl + CLFB_OFF);       // [16] x 128B stride

  const int nb    = mem * 64 + wave * 16;  // this wave's fused-gate col base
  const int ar    = lane & 15;
  const int kx    = (lane >> 4) << 3;      // 0,8,16,24 (ushort units)
  const int crow0 = c * ROWS_CL;
  const int row   = crow0 + mem;           // batch row (valid when mem<16)
  const int wrow  = wave * 16 + ar;        // local W col in LDS

  // ---- stage W slice into LDS (XOR-swizzled rows) ----
  {
    const char* wsrc = (const char*)(Wb + (size_t)(mem * 64) * 1024);
#pragma unroll
    for (int it = 0; it < 32; ++it) {
      int idx16 = it * 256 + tid;           // 8192 x 16B chunks
      int r  = idx16 >> 7;                  // 0..63
      int kb = (idx16 & 127) << 4;          // byte offset in row
      short8 w = *(const short8*)(wsrc + (size_t)r * 2048 + kb);
      *(short8*)((char*)wlds + (size_t)r * 2048 + (kb ^ ((r & 7) << 4))) = w;
    }
  }
  // swizzled B-frag read: col wrow, k-tile KT, 16B at k-byte (KT*64 + kx*2)
#define WFRAG(KT) (*(const short8*)((const char*)wlds + (size_t)wrow * 2048 + \
                    ((((KT) * 64) + (kx << 1)) ^ ((ar & 7) << 4))))

  float btr[8];
  {
    const int e0 = lane << 3;
#pragma unroll
    for (int j = 0; j < 8; ++j) btr[j] = bt[wave * DH + e0 + j];
  }
  __syncthreads();

  float c0 = 0.f, c1 = 0.f;
  f32x4 accE = {0.f, 0.f, 0.f, 0.f}, accO = {0.f, 0.f, 0.f, 0.f};

#define XPART(TT) do {                                                        \
    accE = (f32x4){0.f, 0.f, 0.f, 0.f};                                       \
    accO = (f32x4){0.f, 0.f, 0.f, 0.f};                                       \
    const ushort* Ax = Xb + ((size_t)(TT) * BATCH + crow0 + ar) * DIN + kx;   \
    _Pragma("unroll")                                                         \
    for (int kt = 0; kt < 16; kt += 2) {                                      \
      short8 a0 = *(const short8*)(Ax + kt * 32);                             \
      short8 a1 = *(const short8*)(Ax + (kt + 1) * 32);                       \
      accE = __builtin_amdgcn_mfma_f32_16x16x32_bf16(a0, WFRAG(kt), accE, 0, 0, 0);     \
      accO = __builtin_amdgcn_mfma_f32_16x16x32_bf16(a1, WFRAG(kt + 1), accO, 0, 0, 0); \
    }                                                                         \
  } while (0)

  XPART(0);

  for (int t = 0; t < T_STEPS; ++t) {
    const int ep = t + 1;
    // ---- h-part GEMM: A = h (coherence-point loads), B = LDS W frags ----
    {
      U16 af[16];
#pragma unroll
      for (int kt = 0; kt < 16; ++kt) {
        const u64* p = h_cl + (((size_t)ar * DH + kt * 32 + kx) >> 2);
        af[kt].q[0] = ald64(p);
        af[kt].q[1] = ald64(p + 1);
      }
#pragma unroll
      for (int kt = 0; kt < 16; kt += 2) {
        accE = __builtin_amdgcn_mfma_f32_16x16x32_bf16(af[kt].s,     WFRAG(16 + kt),     accE, 0, 0, 0);
        accO = __builtin_amdgcn_mfma_f32_16x16x32_bf16(af[kt + 1].s, WFRAG(16 + kt + 1), accO, 0, 0, 0);
      }
    }
    // ---- v slice store (coherence point): C row=(lane>>4)*4+r, col=ar ----
    {
      const int rbase = (lane >> 4) << 2;
      float* vp = v_cl + (size_t)rbase * NGATE + nb + ar;
#pragma unroll
      for (int r = 0; r < 4; ++r)
        ast32((uint*)&vp[(size_t)r * NGATE], __float_as_uint(accE[r] + accO[r]));
    }
    __syncthreads();   // drains vmcnt: sc-stores ack'd at coherence point
    if (tid == 0) asti(&slotA[mem * SLOT_STRIDE], ep);

    if (mem < ROWS_CL) {
      // ---- wait for all 32 v slices (32 padded lines, parallel polls) ----
      if (wave == 0) {
        for (;;) {
          int s = (lane < WPC) ? aldi(&slotA[lane * SLOT_STRIDE]) : ep;
          if (__all(s >= ep)) break;
          __builtin_amdgcn_s_sleep(1);
        }
      }
      __syncthreads();
      asm volatile("" ::: "memory");
      // ---- scan row `mem`: wave = gate ----
      {
        const int g  = wave;
        const int e0 = lane << 3;
        const u64* vr = (const u64*)(v_cl + (size_t)mem * NGATE + g * DH + e0);
        UF2 w0, w1, w2, w3;
        w0.q = ald64(vr);     w1.q = ald64(vr + 1);
        w2.q = ald64(vr + 2); w3.q = ald64(vr + 3);
        float p0 = __cosf(w0.f[0] + btr[0]);
        float p1 = __cosf(w0.f[1] + btr[1]);
        float p2 = __cosf(w1.f[0] + btr[2]);
        float p3 = __cosf(w1.f[1] + btr[3]);
        float p4 = __cosf(w2.f[0] + btr[4]);
        float p5 = __cosf(w2.f[1] + btr[5]);
        float p6 = __cosf(w3.f[0] + btr[6]);
        float p7 = __cosf(w3.f[1] + btr[7]);
        float q0 = p0, q1 = q0 * p1, q2 = q1 * p2, q3 = q2 * p3;
        float q4 = q3 * p4, q5 = q4 * p5, q6 = q5 * p6, q7 = q6 * p7;
        float a = q7;
#pragma unroll
        for (int off = 1; off < 64; off <<= 1) {
          float o = __shfl_up(a, off);
          a = (lane >= off) ? a * o : a;
        }
        float ex = __shfl_up(a, 1);
        ex = (lane == 0) ? 1.f : ex;
        float G0 = ex * q0, G1 = ex * q1, G2 = ex * q2, G3 = ex * q3;
        float G4 = ex * q4, G5 = ex * q5, G6 = ex * q6, G7 = ex * q7;
        float4 r0, r1;
        if (g == 2) {
          r0 = make_float4(tanhf_(G0), tanhf_(G1), tanhf_(G2), tanhf_(G3));
          r1 = make_float4(tanhf_(G4), tanhf_(G5), tanhf_(G6), tanhf_(G7));
        } else {
          r0 = make_float4(sigm(G0), sigm(G1), sigm(G2), sigm(G3));
          r1 = make_float4(sigm(G4), sigm(G5), sigm(G6), sigm(G7));
        }
        *(float4*)&lds_g[g * DH + e0]     = r0;
        *(float4*)&lds_g[g * DH + e0 + 4] = r1;
      }
      __syncthreads();
      {
        const int k = tid << 1;
        float f0 = lds_g[0 * DH + k], f1 = lds_g[0 * DH + k + 1];
        float i0 = lds_g[1 * DH + k], i1 = lds_g[1 * DH + k + 1];
        float u0 = lds_g[2 * DH + k], u1 = lds_g[2 * DH + k + 1];
        float o0 = lds_g[3 * DH + k], o1 = lds_g[3 * DH + k + 1];
        c0 = f0 * c0 + i0 * u0;
        c1 = f1 * c1 + i1 * u1;
        float h0 = o0 * tanhf_(c0);
        float h1 = o1 * tanhf_(c1);
        float2 hp = make_float2(h0, h1);
        *(float2*)&out[((size_t)t * BATCH + row) * DH + k] = hp;
        uint hbits = ((uint)f2bf(h1) << 16) | (uint)f2bf(h0);
        ast32(&h_cl32[((size_t)mem * DH + k) >> 1], hbits);
        if (t == T_STEPS - 1) {
          *(float2*)&out[OUT_HX + (size_t)row * DH + k] = hp;
          float2 cp = make_float2(c0, c1);
          *(float2*)&out[OUT_CX + (size_t)row * DH + k] = cp;
        }
      }
      __syncthreads();   // drain h sc-stores
      if (tid == 0) asti(&slotB[mem * SLOT_STRIDE], ep);
    }

    if (t + 1 < T_STEPS) {
      // ---- overlapped x-part of t+1 (needs no h) ----
      XPART(t + 1);
      // ---- wait for all 16 h rows (16 padded lines) ----
      if (wave == 0) {
        for (;;) {
          int s = (lane < ROWS_CL) ? aldi(&slotB[lane * SLOT_STRIDE]) : ep;
          if (__all(s >= ep)) break;
          __builtin_amdgcn_s_sleep(1);
        }
      }
      __syncthreads();
      asm volatile("" ::: "memory");
    }
  }
#undef XPART
#undef WFRAG
}

extern "C" void kernel_launch(void* const* d_in, const int* in_sizes, int n_in,
                              void* d_out, int out_size, void* d_ws, size_t ws_size,
                              hipStream_t stream) {
  const float* X  = (const float*)d_in[0];
  const float* Wf = (const float*)d_in[1];
  const float* bf = (const float*)d_in[2];
  const float* tf = (const float*)d_in[3];
  const float* Wi = (const float*)d_in[4];
  const float* bi = (const float*)d_in[5];
  const float* ti = (const float*)d_in[6];
  const float* Wu = (const float*)d_in[7];
  const float* bu = (const float*)d_in[8];
  const float* tu = (const float*)d_in[9];
  const float* Wo = (const float*)d_in[10];
  const float* bo = (const float*)d_in[11];
  const float* to = (const float*)d_in[12];

  char* ws = (char*)d_ws;
  ushort* Wb     = (ushort*)(ws + WB_OFF);
  ushort* Xb     = (ushort*)(ws + XB_OFF);
  float*  bt     = (float*)(ws + BT_OFF);
  char*   clbase = ws + CL_OFF;
  float*  out    = (float*)d_out;

  static bool attr_set = false;
  if (!attr_set) {
    hipFuncSetAttribute((const void*)qlstm_main,
                        hipFuncAttributeMaxDynamicSharedMemorySize, LDS_TOTAL);
    attr_set = true;
  }

  k_prep_w<<<dim3((NGATE * 1024 / 4 + 255) / 256), dim3(256), 0, stream>>>(Wf, Wi, Wu, Wo, Wb);
  k_prep_x<<<dim3((T_STEPS * BATCH * DIN / 4 + 255) / 256), dim3(256), 0, stream>>>(X, Xb);
  k_prep_misc<<<dim3(256), dim3(256), 0, stream>>>(bf, tf, bi, ti, bu, tu, bo, to, bt, clbase);
  qlstm_main<<<dim3(NWG), dim3(256), LDS_TOTAL, stream>>>(Xb, Wb, bt, clbase, out);
}